// Round 2
// baseline (3313.031 us; speedup 1.0000x reference)
//
#include <hip/hip_runtime.h>
#include <stdint.h>

// ---------------- problem constants ----------------
#define B_   64
#define T_   256
#define E_   300
#define H_   512
#define PAD_ 1
#define BT_  16384            // B_*T_
#define KP   384              // E padded to 3*128 (wave K-split 96 = 3x32)
#define G_   64               // blocks per group in recurrence
#define HXG  16384            // one group hx plane: 32*512 elements
#define HXS  32768            // per-step plane stride (2 groups)

typedef __attribute__((ext_vector_type(8))) short short8;
typedef __attribute__((ext_vector_type(4))) float f32x4;
typedef __attribute__((ext_vector_type(4))) unsigned short us4;
typedef __attribute__((ext_vector_type(8))) unsigned short us8;

// ---------------- helpers ----------------
__device__ __forceinline__ uint16_t f2bf(float f) {           // RNE float->bf16
  uint32_t x = __builtin_bit_cast(uint32_t, f);
  x += 0x7fffu + ((x >> 16) & 1u);
  return (uint16_t)(x >> 16);
}
__device__ __forceinline__ float bf2f(uint16_t u) {
  return __builtin_bit_cast(float, (uint32_t)u << 16);
}
__device__ __forceinline__ float fsig(float x)  { return 1.f / (1.f + __expf(-x)); }
__device__ __forceinline__ float ftanh(float x) { return 1.f - 2.f / (__expf(2.f * x) + 1.f); }

// coherence-point (MALL) accesses: bypass XCD-private L1/L2; self-draining
// (vmcnt(0) inside) so compiler vmcnt bookkeeping stays valid.
__device__ __forceinline__ unsigned ld_cp(const unsigned* p) {
  unsigned v;
  asm volatile("global_load_dword %0, %1, off sc0 sc1\n\ts_waitcnt vmcnt(0)"
               : "=v"(v) : "v"(p) : "memory");
  return v;
}
__device__ __forceinline__ void st_cp(unsigned* p, unsigned v) {
  asm volatile("global_store_dword %0, %1, off sc0 sc1" :: "v"(p), "v"(v) : "memory");
}
// wave-parallel arrival check: lane i polls flag slot i (64B-strided, one line
// per lane -> no single-line hot spot, no RMW). Returns when ALL flags >= tgt.
__device__ __forceinline__ void wait_flags(const unsigned* fb, unsigned tgt) {
  const unsigned* p = fb + (threadIdx.x & 63) * 16;
  unsigned v = ld_cp(p);
  while (!__all((int)(v >= tgt))) {
    __builtin_amdgcn_s_sleep(1);
    v = ld_cp(p);
  }
}

__device__ __forceinline__ void split4(f32x4 v, us4& hi, us4& lo) {
  #pragma unroll
  for (int j = 0; j < 4; ++j) {
    uint16_t h = f2bf(v[j]);
    hi[j] = h;
    lo[j] = f2bf(v[j] - bf2f(h));
  }
}

// ---------------- prep: fp32 -> bf16 hi/lo planes, gathers, zero-init ----------------
__global__ void prep_kernel(
    const float* __restrict__ emb, const float* __restrict__ W_ih,
    const float* __restrict__ b_ih, const float* __restrict__ W_hh,
    const float* __restrict__ b_hh, const float* __restrict__ aW1,
    const float* __restrict__ ab1, const int* __restrict__ x,
    uint16_t* ApH, uint16_t* ApL, uint16_t* WihH, uint16_t* WihL,
    uint16_t* WhhH, uint16_t* WhhL, uint16_t* AW1e,
    float* s1bias, float* biasg,
    uint16_t* hxH, uint16_t* hxL, float* amask, float* last, unsigned* cnts)
{
  int id = blockIdx.x * 256 + threadIdx.x;
  if (id < 1572864) {                       // Ap hi/lo [m=t*64+b][384]
    int m = id / 96, c = id % 96;
    int t = m >> 6, b = m & 63;
    int tok = x[b * T_ + t];
    f32x4 v = (f32x4){0.f, 0.f, 0.f, 0.f};
    if (tok != PAD_ && c < 75) v = *(const f32x4*)(emb + (size_t)tok * 300 + c * 4);
    us4 hi, lo; split4(v, hi, lo);
    *(us4*)(ApH + (size_t)m * KP + c * 4) = hi;
    *(us4*)(ApL + (size_t)m * KP + c * 4) = lo;
    return;
  }
  id -= 1572864;
  if (id < 196608) {                        // Wih hi/lo [2048][384]
    int n = id / 96, c = id % 96;
    f32x4 v = (f32x4){0.f, 0.f, 0.f, 0.f};
    if (c < 75) v = *(const f32x4*)(W_ih + (size_t)n * 300 + c * 4);
    us4 hi, lo; split4(v, hi, lo);
    *(us4*)(WihH + (size_t)n * KP + c * 4) = hi;
    *(us4*)(WihL + (size_t)n * KP + c * 4) = lo;
    return;
  }
  id -= 196608;
  if (id < 262144) {                        // Whh hi/lo [2048][512]
    int n = id / 128, c = id % 128;
    f32x4 v = *(const f32x4*)(W_hh + (size_t)n * 512 + c * 4);
    us4 hi, lo; split4(v, hi, lo);
    *(us4*)(WhhH + (size_t)n * 512 + c * 4) = hi;
    *(us4*)(WhhL + (size_t)n * 512 + c * 4) = lo;
    return;
  }
  id -= 262144;
  if (id < 36864) {                         // AW1e[384][384] (hi only): aW1[:,:300] padded
    int e = id / 96, c = id % 96;
    f32x4 v = (f32x4){0.f, 0.f, 0.f, 0.f};
    if (e < 300 && c < 75) v = *(const f32x4*)(aW1 + (size_t)e * 812 + c * 4);
    us4 hi;
    #pragma unroll
    for (int j = 0; j < 4; ++j) hi[j] = f2bf(v[j]);
    *(us4*)(AW1e + (size_t)e * KP + c * 4) = hi;
    return;
  }
  id -= 36864;
  if (id < 384) { s1bias[id] = (id < 300) ? ab1[id] : 0.f; return; }
  id -= 384;
  if (id < 2048) { biasg[id] = b_ih[id] + b_hh[id]; return; }
  id -= 2048;
  if (id < 8192) {                          // zero HX[0] (both groups) hi+lo
    ((us4*)hxH)[id] = (us4){0, 0, 0, 0};
    ((us4*)hxL)[id] = (us4){0, 0, 0, 0};
    return;
  }
  id -= 8192;
  if (id < 16384) {                         // amask[t*64+b]
    int t = id >> 6, b = id & 63;
    amask[id] = (x[b * T_ + t] == PAD_) ? 0.f : 1.f;
    return;
  }
  id -= 16384;
  if (id < 8192) { ((f32x4*)last)[id] = (f32x4){0.f, 0.f, 0.f, 0.f}; return; }
  id -= 8192;
  if (id < 4096) cnts[id] = 0u;             // all per-block arrival flags (2 iters)
}

// ---------------- attention s1 GEMM: S1(bf16) = Ap_hi @ AW1e^T + ab1 ----------------
__global__ __launch_bounds__(256) void gemm_s1(
    const uint16_t* __restrict__ Ap, const uint16_t* __restrict__ Bw,
    const float* __restrict__ bias, uint16_t* __restrict__ C)
{
  const int nt = blockIdx.x;                // 0..2
  const int mt = blockIdx.y;                // 0..127
  const int tid = threadIdx.x;
  const int lane = tid & 63, w = tid >> 6;
  const int wm = w >> 1, wn = w & 1;
  const int l15 = lane & 15, lq = lane >> 4;
  __shared__ uint16_t As[128 * 64];
  __shared__ uint16_t Bs[128 * 64];
  f32x4 acc[4][4];
  #pragma unroll
  for (int i = 0; i < 4; ++i)
    #pragma unroll
    for (int j = 0; j < 4; ++j) acc[i][j] = (f32x4){0.f, 0.f, 0.f, 0.f};

  for (int kb = 0; kb < KP; kb += 64) {
    __syncthreads();
    #pragma unroll
    for (int c = 0; c < 4; ++c) {
      int lin = c * 256 + tid;
      int row = lin >> 3, col = (lin & 7) * 8;
      *(us8*)(As + row * 64 + col) = *(const us8*)(Ap + (size_t)(mt * 128 + row) * KP + kb + col);
      *(us8*)(Bs + row * 64 + col) = *(const us8*)(Bw + (size_t)(nt * 128 + row) * KP + kb + col);
    }
    __syncthreads();
    #pragma unroll
    for (int ks = 0; ks < 2; ++ks) {
      const int kk = ks * 32 + lq * 8;
      short8 af[4], bf[4];
      #pragma unroll
      for (int i = 0; i < 4; ++i) af[i] = *(const short8*)(As + (wm * 64 + i * 16 + l15) * 64 + kk);
      #pragma unroll
      for (int i = 0; i < 4; ++i) bf[i] = *(const short8*)(Bs + (wn * 64 + i * 16 + l15) * 64 + kk);
      #pragma unroll
      for (int i = 0; i < 4; ++i)
        #pragma unroll
        for (int j = 0; j < 4; ++j)
          acc[i][j] = __builtin_amdgcn_mfma_f32_16x16x32_bf16(af[i], bf[j], acc[i][j], 0, 0, 0);
    }
  }
  #pragma unroll
  for (int j = 0; j < 4; ++j) {
    const int n = nt * 128 + wn * 64 + j * 16 + l15;
    const float bv = bias[n];
    #pragma unroll
    for (int i = 0; i < 4; ++i) {
      const int mrow = mt * 128 + wm * 64 + i * 16 + lq * 4;
      uint16_t* cp = C + (size_t)mrow * KP + n;
      #pragma unroll
      for (int r = 0; r < 4; ++r) cp[(size_t)r * KP] = f2bf(acc[i][j][r] + bv);
    }
  }
}

// ---------------- persistent LSTM recurrence, 2 independent batch groups ----------------
// grid = 128: group g = blockIdx&1 owns samples [g*32, g*32+32); bk = blockIdx>>1 owns
// hidden units [bk*8, bk*8+8). hx in per-step per-group buffers; publishes sc0/sc1
// write-through. Sync: per-block arrival FLAGS (64 x 64B-strided dwords per group) —
// publisher does one plain sc0/sc1 store (no RMW); wave 0 of each waiter polls all 64
// flags with a single wave64 load + ballot. No single-line RMW serialization.
__global__ __launch_bounds__(256, 1) void rec_kernel(
    const uint16_t* __restrict__ WhhH, const uint16_t* __restrict__ WhhL,
    const uint16_t* __restrict__ WihH, const uint16_t* __restrict__ WihL,
    const uint16_t* __restrict__ ApH, const uint16_t* __restrict__ ApL,
    const float* __restrict__ biasg,     // [2048] b_ih+b_hh
    const float* __restrict__ aarr,      // [T_*64] gate a (mask or att*mask)
    uint16_t* __restrict__ hxH,          // this iter's HX hi base (t=0 plane)
    uint16_t* __restrict__ hxL,
    float* __restrict__ last,            // [64][512] fp32: init in, final out
    unsigned* __restrict__ flags)        // this iter's flags (g*1024 dword stride)
{
  const int tid = threadIdx.x;
  const int g  = blockIdx.x & 1;
  const int bk = blockIdx.x >> 1;
  const int lane = tid & 63, w = tid >> 6;
  const int l15 = lane & 15, lq = lane >> 4;
  const int gh = l15 >> 3, uu = l15 & 7;

  unsigned* gflag  = flags + g * 1024;     // 64 flags x 16 dwords (64B apart)
  unsigned* myflag = gflag + bk * 16;

  // weight fragments resident in VGPRs: n-tile n2 cols 0..7 -> gate 2*n2, 8..15 -> 2*n2+1
  short8 bhhH[2][4], bhhL[2][4], bihH[2][3], bihL[2][3];
  #pragma unroll
  for (int n2 = 0; n2 < 2; ++n2) {
    const int n = (n2 * 2 + gh) * 512 + bk * 8 + uu;
    #pragma unroll
    for (int ks = 0; ks < 4; ++ks) {
      const size_t off = (size_t)n * 512 + w * 128 + ks * 32 + lq * 8;
      bhhH[n2][ks] = *(const short8*)(WhhH + off);
      bhhL[n2][ks] = *(const short8*)(WhhL + off);
    }
    #pragma unroll
    for (int kb = 0; kb < 3; ++kb) {
      const size_t off = (size_t)n * KP + w * 96 + kb * 32 + lq * 8;
      bihH[n2][kb] = *(const short8*)(WihH + off);
      bihL[n2][kb] = *(const short8*)(WihL + off);
    }
  }

  // epilogue ownership (tid<128): sample eb (group-local), units (eu, eu+1)
  const int eb = tid >> 2;                 // 0..31 for tid<128
  const int eu = (tid & 3) * 2;
  const int gb = g * 32 + eb;              // global batch index
  float2 bg2[4];
  float hprev0 = 0.f, hprev1 = 0.f, cprev0 = 0.f, cprev1 = 0.f;
  if (tid < 128) {
    #pragma unroll
    for (int gg = 0; gg < 4; ++gg) bg2[gg] = *(const float2*)(biasg + gg * 512 + bk * 8 + eu);
    hprev0 = last[gb * 512 + bk * 8 + eu];
    hprev1 = last[gb * 512 + bk * 8 + eu + 1];
  }

  __shared__ float part[4][32][36];        // K-split partials; stride 36 -> 2-way (free)

  #pragma clang loop unroll(disable)
  for (int t = 0; t < T_; ++t) {
    const size_t ap_base = (size_t)t * 64 * KP + (size_t)g * 32 * KP;

    f32x4 acc[2][2];
    #pragma unroll
    for (int mi = 0; mi < 2; ++mi) { acc[mi][0] = (f32x4){0,0,0,0}; acc[mi][1] = (f32x4){0,0,0,0}; }

    // (A) input-side gates: xe @ W_ih^T — no dependence on other blocks
    #pragma unroll
    for (int kb = 0; kb < 3; ++kb) {
      const int k = w * 96 + kb * 32 + lq * 8;
      #pragma unroll
      for (int mi = 0; mi < 2; ++mi) {
        const size_t aoff = ap_base + (size_t)(mi * 16 + l15) * KP + k;
        short8 aH = *(const short8*)(ApH + aoff);
        short8 aL = *(const short8*)(ApL + aoff);
        #pragma unroll
        for (int n2 = 0; n2 < 2; ++n2) {
          acc[mi][n2] = __builtin_amdgcn_mfma_f32_16x16x32_bf16(aH, bihH[n2][kb], acc[mi][n2], 0, 0, 0);
          acc[mi][n2] = __builtin_amdgcn_mfma_f32_16x16x32_bf16(aH, bihL[n2][kb], acc[mi][n2], 0, 0, 0);
          acc[mi][n2] = __builtin_amdgcn_mfma_f32_16x16x32_bf16(aL, bihH[n2][kb], acc[mi][n2], 0, 0, 0);
        }
      }
    }
    const float a = (tid < 128) ? aarr[t * 64 + gb] : 0.f;

    // (B) wait: all group blocks published hx[t]  (every flag >= t); wave 0 polls
    if (t > 0) {
      if (tid < 64) wait_flags(gflag, (unsigned)t);
      __syncthreads();
    }

    // (C) recurrent gates: hx[t] @ W_hh^T (plain loads; per-step buffer is fresh)
    const uint16_t* hh = hxH + ((size_t)t * 2 + g) * HXG;
    const uint16_t* hl = hxL + ((size_t)t * 2 + g) * HXG;
    #pragma unroll
    for (int ks = 0; ks < 4; ++ks) {
      const int k = w * 128 + ks * 32 + lq * 8;
      #pragma unroll
      for (int mi = 0; mi < 2; ++mi) {
        const int m = mi * 16 + l15;
        short8 hH = *(const short8*)(hh + m * 512 + k);
        short8 hL = *(const short8*)(hl + m * 512 + k);
        #pragma unroll
        for (int n2 = 0; n2 < 2; ++n2) {
          acc[mi][n2] = __builtin_amdgcn_mfma_f32_16x16x32_bf16(hH, bhhH[n2][ks], acc[mi][n2], 0, 0, 0);
          acc[mi][n2] = __builtin_amdgcn_mfma_f32_16x16x32_bf16(hH, bhhL[n2][ks], acc[mi][n2], 0, 0, 0);
          acc[mi][n2] = __builtin_amdgcn_mfma_f32_16x16x32_bf16(hL, bhhH[n2][ks], acc[mi][n2], 0, 0, 0);
        }
      }
    }

    // (D) K-partials to LDS: D row=(lq*4+r)=sample, col=l15 within n-tile
    #pragma unroll
    for (int mi = 0; mi < 2; ++mi)
      #pragma unroll
      for (int n2 = 0; n2 < 2; ++n2)
        #pragma unroll
        for (int r = 0; r < 4; ++r)
          part[w][mi * 16 + lq * 4 + r][n2 * 16 + l15] = acc[mi][n2][r];

    __syncthreads();

    // (E) epilogue: gates -> gated (c,h) update; publish hx[t+1]
    if (tid < 128) {
      float gv0[4], gv1[4];
      #pragma unroll
      for (int gg = 0; gg < 4; ++gg) {
        float s0 = bg2[gg].x, s1 = bg2[gg].y;
        #pragma unroll
        for (int ww = 0; ww < 4; ++ww) {
          s0 += part[ww][eb][gg * 8 + eu];
          s1 += part[ww][eb][gg * 8 + eu + 1];
        }
        gv0[gg] = s0; gv1[gg] = s1;
      }
      float i0 = fsig(gv0[0]), f0 = fsig(gv0[1]), g0 = ftanh(gv0[2]), o0 = fsig(gv0[3]);
      float i1 = fsig(gv1[0]), f1 = fsig(gv1[1]), g1 = ftanh(gv1[2]), o1 = fsig(gv1[3]);
      float cn0 = f0 * cprev0 + i0 * g0;
      float cn1 = f1 * cprev1 + i1 * g1;
      float hn0 = o0 * ftanh(cn0);
      float hn1 = o1 * ftanh(cn1);
      float h0 = a * hn0 + (1.f - a) * hprev0;
      float h1 = a * hn1 + (1.f - a) * hprev1;
      cprev0 = a * cn0 + (1.f - a) * cprev0;
      cprev1 = a * cn1 + (1.f - a) * cprev1;
      hprev0 = h0; hprev1 = h1;

      uint16_t b0 = f2bf(h0), b1 = f2bf(h1);
      uint16_t l0 = f2bf(h0 - bf2f(b0)), l1 = f2bf(h1 - bf2f(b1));
      const size_t o = ((size_t)(t + 1) * 2 + g) * HXG + eb * 512 + bk * 8 + eu;
      st_cp((unsigned*)(hxH + o), (uint32_t)b0 | ((uint32_t)b1 << 16));
      st_cp((unsigned*)(hxL + o), (uint32_t)l0 | ((uint32_t)l1 << 16));
      if (t == T_ - 1) {
        float2 lv; lv.x = h0; lv.y = h1;
        *(float2*)(last + gb * 512 + bk * 8 + eu) = lv;
      }
    }
    if (t < T_ - 1) {
      asm volatile("s_waitcnt vmcnt(0)" ::: "memory");   // hx stores acked at MALL
      __syncthreads();                                   // whole block drained
      if (tid == 0) st_cp(myflag, (unsigned)(t + 1));    // plain flag store, no RMW
    }
  }
}

// ---------------- attention between iterations (all fp32) ----------------
__global__ void att1_kernel(const float* __restrict__ last, const float* __restrict__ aW1,
                            float* __restrict__ hterm) {
  int id = blockIdx.x * 256 + threadIdx.x;           // 64*300
  if (id >= 64 * 300) return;
  int b = id / 300, e = id % 300;
  const float* lr = last + b * 512;
  const float* wr = aW1 + (size_t)e * 812 + 300;     // aW1[e, E+k]
  float s = 0.f;
  #pragma unroll 8
  for (int k = 0; k < 512; ++k) s += lr[k] * wr[k];
  hterm[b * 300 + e] = s;
}

__global__ void att2_kernel(const uint16_t* __restrict__ S1, const float* __restrict__ hterm,
                            const float* __restrict__ aW2, const float* __restrict__ ab2,
                            const float* __restrict__ amask, float* __restrict__ att) {
  int id = blockIdx.x * 128 + threadIdx.x;           // t*64+b
  if (id >= BT_) return;
  int b = id & 63;
  const uint16_t* s1 = S1 + (size_t)id * KP;         // inp@aW1[:,:E]^T + ab1 (bf16)
  const float* ht = hterm + b * 300;
  float s = ab2[0];
  for (int e = 0; e < 300; ++e) s += ftanh(bf2f(s1[e]) + ht[e]) * aW2[e];
  att[id] = amask[id] * fsig(s);
}

// ---------------- final logits (fp32 in, fp32 out) ----------------
__global__ void logits_kernel(const float* __restrict__ last, const float* __restrict__ Wout,
                              const float* __restrict__ bout, float* __restrict__ out) {
  int tid = threadIdx.x;                             // 320 = 64*5
  if (tid >= 320) return;
  int b = tid / 5, o = tid % 5;
  const float* lr = last + b * 512;
  const float* wr = Wout + o * 512;
  float s = bout[o];
  #pragma unroll 8
  for (int k = 0; k < 512; ++k) s += lr[k] * wr[k];
  out[tid] = s;
}

// ---------------- workspace layout (bytes, 256-aligned) ----------------
#define OFF_APHI  ((size_t)0)            // 16384*384*2 = 12,582,912
#define OFF_APLO  ((size_t)12582912)
#define OFF_WIHHI ((size_t)25165824)     // 2048*384*2 = 1,572,864
#define OFF_WIHLO ((size_t)26738688)
#define OFF_WHHHI ((size_t)28311552)     // 2048*512*2 = 2,097,152
#define OFF_WHHLO ((size_t)30408704)
#define OFF_AW1E  ((size_t)32505856)     // 384*384*2 = 294,912
#define OFF_S1    ((size_t)32800768)     // 16384*384*2 = 12,582,912 (bf16)
#define OFF_S1B   ((size_t)45383680)     // 1536
#define OFF_BG    ((size_t)45385216)     // 8192
#define OFF_HXH   ((size_t)45393408)     // 513*65536 = 33,619,968
#define OFF_HXL   ((size_t)79013376)     // 33,619,968
#define OFF_AMASK ((size_t)112633344)    // 65,536
#define OFF_ATT   ((size_t)112698880)    // 65,536
#define OFF_HT    ((size_t)112764416)    // 76,800
#define OFF_LAST  ((size_t)112841216)    // 131,072
#define OFF_CNT   ((size_t)112972288)    // 16,384 (2 iters x 2 groups x 64 flags x 64B)
#define WS_NEED   ((size_t)112988672)

extern "C" void kernel_launch(void* const* d_in, const int* in_sizes, int n_in,
                              void* d_out, int out_size, void* d_ws, size_t ws_size,
                              hipStream_t stream) {
  const float* emb  = (const float*)d_in[0];
  const float* W_ih = (const float*)d_in[1];
  const float* b_ih = (const float*)d_in[2];
  const float* W_hh = (const float*)d_in[3];
  const float* b_hh = (const float*)d_in[4];
  const float* aW1  = (const float*)d_in[5];
  const float* ab1  = (const float*)d_in[6];
  const float* aW2  = (const float*)d_in[7];
  const float* ab2  = (const float*)d_in[8];
  const float* Wout = (const float*)d_in[9];
  const float* bout = (const float*)d_in[10];
  const int*   x    = (const int*)d_in[11];

  if (ws_size < WS_NEED) return;  // guarded fail: d_out stays zero (diagnostic)

  char* ws = (char*)d_ws;
  uint16_t* ApH    = (uint16_t*)(ws + OFF_APHI);
  uint16_t* ApL    = (uint16_t*)(ws + OFF_APLO);
  uint16_t* WihH   = (uint16_t*)(ws + OFF_WIHHI);
  uint16_t* WihL   = (uint16_t*)(ws + OFF_WIHLO);
  uint16_t* WhhH   = (uint16_t*)(ws + OFF_WHHHI);
  uint16_t* WhhL   = (uint16_t*)(ws + OFF_WHHLO);
  uint16_t* AW1e   = (uint16_t*)(ws + OFF_AW1E);
  uint16_t* S1     = (uint16_t*)(ws + OFF_S1);
  float*    s1bias = (float*)(ws + OFF_S1B);
  float*    biasg  = (float*)(ws + OFF_BG);
  uint16_t* HXH    = (uint16_t*)(ws + OFF_HXH);
  uint16_t* HXL    = (uint16_t*)(ws + OFF_HXL);
  float*    amask  = (float*)(ws + OFF_AMASK);
  float*    att    = (float*)(ws + OFF_ATT);
  float*    hterm  = (float*)(ws + OFF_HT);
  float*    last   = (float*)(ws + OFF_LAST);
  unsigned* cnt0   = (unsigned*)(ws + OFF_CNT);
  unsigned* cnt1   = cnt0 + 2048;          // second iter's flag plane (8KB each)

  prep_kernel<<<8234, 256, 0, stream>>>(emb, W_ih, b_ih, W_hh, b_hh, aW1, ab1, x,
                                        ApH, ApL, WihH, WihL, WhhH, WhhL, AW1e,
                                        s1bias, biasg, HXH, HXL, amask, last, cnt0);
  gemm_s1<<<dim3(3, 128), 256, 0, stream>>>(ApH, AW1e, s1bias, S1);
  // iter 0: a = pad mask; HX planes [0..256]
  rec_kernel<<<2 * G_, 256, 0, stream>>>(WhhH, WhhL, WihH, WihL, ApH, ApL,
                                         biasg, amask, HXH, HXL, last, cnt0);
  att1_kernel<<<75, 256, 0, stream>>>(last, aW1, hterm);
  att2_kernel<<<128, 128, 0, stream>>>(S1, hterm, aW2, ab2, amask, att);
  // iter 1: a = attention * mask; HX base shifted so its t=0 plane = iter0's final
  rec_kernel<<<2 * G_, 256, 0, stream>>>(WhhH, WhhL, WihH, WihL, ApH, ApL,
                                         biasg, att, HXH + (size_t)256 * HXS,
                                         HXL + (size_t)256 * HXS, last, cnt1);
  logits_kernel<<<1, 320, 0, stream>>>(last, Wout, bout, (float*)d_out);
}

// Round 3
// 2780.138 us; speedup vs baseline: 1.1917x; 1.1917x over previous
//
#include <hip/hip_runtime.h>
#include <stdint.h>

// ---------------- problem constants ----------------
#define B_   64
#define T_   256
#define E_   300
#define H_   512
#define PAD_ 1
#define BT_  16384            // B_*T_
#define KP   384              // E padded to 3*128 (wave K-split 96 = 3x32)
#define G_   64               // blocks per group in recurrence
#define HXG  16384            // one group hx plane: 32*512 elements
#define HXS  32768            // per-step plane stride (2 groups)

typedef __attribute__((ext_vector_type(8))) short short8;
typedef __attribute__((ext_vector_type(4))) float f32x4;
typedef __attribute__((ext_vector_type(4))) unsigned short us4;
typedef __attribute__((ext_vector_type(8))) unsigned short us8;
typedef __attribute__((ext_vector_type(4))) unsigned int u32x4;

// ---------------- helpers ----------------
__device__ __forceinline__ uint16_t f2bf(float f) {           // RNE float->bf16
  uint32_t x = __builtin_bit_cast(uint32_t, f);
  x += 0x7fffu + ((x >> 16) & 1u);
  return (uint16_t)(x >> 16);
}
__device__ __forceinline__ float bf2f(uint16_t u) {
  return __builtin_bit_cast(float, (uint32_t)u << 16);
}
__device__ __forceinline__ float fsig(float x)  { return 1.f / (1.f + __expf(-x)); }
__device__ __forceinline__ float ftanh(float x) { return 1.f - 2.f / (__expf(2.f * x) + 1.f); }

// coherence-point (MALL) accesses: bypass XCD-private L1/L2.
__device__ __forceinline__ void st_cp(unsigned* p, unsigned v) {
  asm volatile("global_store_dword %0, %1, off sc0 sc1" :: "v"(p), "v"(v) : "memory");
}
// pipelined 16B coherent load, no individual wait (batch + one vmcnt(0))
__device__ __forceinline__ void ldg_cp16(u32x4& d, const uint16_t* p) {
  asm volatile("global_load_dwordx4 %0, %1, off sc0 sc1" : "=v"(d) : "v"(p));
}

__device__ __forceinline__ void split4(f32x4 v, us4& hi, us4& lo) {
  #pragma unroll
  for (int j = 0; j < 4; ++j) {
    uint16_t h = f2bf(v[j]);
    hi[j] = h;
    lo[j] = f2bf(v[j] - bf2f(h));
  }
}

// ---------------- prep: fp32 -> bf16 hi/lo planes, gathers, poison, zero-init ----------------
__global__ void prep_kernel(
    const float* __restrict__ emb, const float* __restrict__ W_ih,
    const float* __restrict__ b_ih, const float* __restrict__ W_hh,
    const float* __restrict__ b_hh, const float* __restrict__ aW1,
    const float* __restrict__ ab1, const int* __restrict__ x,
    uint16_t* ApH, uint16_t* ApL, uint16_t* WihH, uint16_t* WihL,
    uint16_t* WhhH, uint16_t* WhhL, uint16_t* AW1e,
    float* s1bias, float* biasg,
    uint16_t* hxH, uint16_t* hxL, float* amask, float* last)
{
  int id = blockIdx.x * 256 + threadIdx.x;
  if (id < 1572864) {                       // Ap hi/lo [m=t*64+b][384]
    int m = id / 96, c = id % 96;
    int t = m >> 6, b = m & 63;
    int tok = x[b * T_ + t];
    f32x4 v = (f32x4){0.f, 0.f, 0.f, 0.f};
    if (tok != PAD_ && c < 75) v = *(const f32x4*)(emb + (size_t)tok * 300 + c * 4);
    us4 hi, lo; split4(v, hi, lo);
    *(us4*)(ApH + (size_t)m * KP + c * 4) = hi;
    *(us4*)(ApL + (size_t)m * KP + c * 4) = lo;
    return;
  }
  id -= 1572864;
  if (id < 196608) {                        // Wih hi/lo [2048][384]
    int n = id / 96, c = id % 96;
    f32x4 v = (f32x4){0.f, 0.f, 0.f, 0.f};
    if (c < 75) v = *(const f32x4*)(W_ih + (size_t)n * 300 + c * 4);
    us4 hi, lo; split4(v, hi, lo);
    *(us4*)(WihH + (size_t)n * KP + c * 4) = hi;
    *(us4*)(WihL + (size_t)n * KP + c * 4) = lo;
    return;
  }
  id -= 196608;
  if (id < 262144) {                        // Whh hi/lo [2048][512]
    int n = id / 128, c = id % 128;
    f32x4 v = *(const f32x4*)(W_hh + (size_t)n * 512 + c * 4);
    us4 hi, lo; split4(v, hi, lo);
    *(us4*)(WhhH + (size_t)n * 512 + c * 4) = hi;
    *(us4*)(WhhL + (size_t)n * 512 + c * 4) = lo;
    return;
  }
  id -= 262144;
  if (id < 36864) {                         // AW1e[384][384] (hi only): aW1[:,:300] padded
    int e = id / 96, c = id % 96;
    f32x4 v = (f32x4){0.f, 0.f, 0.f, 0.f};
    if (e < 300 && c < 75) v = *(const f32x4*)(aW1 + (size_t)e * 812 + c * 4);
    us4 hi;
    #pragma unroll
    for (int j = 0; j < 4; ++j) hi[j] = f2bf(v[j]);
    *(us4*)(AW1e + (size_t)e * KP + c * 4) = hi;
    return;
  }
  id -= 36864;
  if (id < 384) { s1bias[id] = (id < 300) ? ab1[id] : 0.f; return; }
  id -= 384;
  if (id < 2048) { biasg[id] = b_ih[id] + b_hh[id]; return; }
  id -= 2048;
  if (id < 8192) {                          // zero HX[0] (both groups) hi+lo
    ((us4*)hxH)[id] = (us4){0, 0, 0, 0};
    ((us4*)hxL)[id] = (us4){0, 0, 0, 0};
    return;
  }
  id -= 8192;
  if (id < 16384) {                         // amask[t*64+b]
    int t = id >> 6, b = id & 63;
    amask[id] = (x[b * T_ + t] == PAD_) ? 0.f : 1.f;
    return;
  }
  id -= 16384;
  if (id < 8192) { ((f32x4*)last)[id] = (f32x4){0.f, 0.f, 0.f, 0.f}; return; }
  id -= 8192;
  if (id < 4194304) {                       // poison HX planes 1..512 (hi+lo): bf16 NaN pair
    const us8 poison = {0xFFFFu,0xFFFFu,0xFFFFu,0xFFFFu,0xFFFFu,0xFFFFu,0xFFFFu,0xFFFFu};
    if (id < 2097152) ((us8*)(hxH + 32768))[id] = poison;
    else              ((us8*)(hxL + 32768))[id - 2097152] = poison;
    return;
  }
}

// ---------------- attention s1 GEMM: S1(bf16) = Ap_hi @ AW1e^T + ab1 ----------------
__global__ __launch_bounds__(256) void gemm_s1(
    const uint16_t* __restrict__ Ap, const uint16_t* __restrict__ Bw,
    const float* __restrict__ bias, uint16_t* __restrict__ C)
{
  const int nt = blockIdx.x;                // 0..2
  const int mt = blockIdx.y;                // 0..127
  const int tid = threadIdx.x;
  const int lane = tid & 63, w = tid >> 6;
  const int wm = w >> 1, wn = w & 1;
  const int l15 = lane & 15, lq = lane >> 4;
  __shared__ uint16_t As[128 * 64];
  __shared__ uint16_t Bs[128 * 64];
  f32x4 acc[4][4];
  #pragma unroll
  for (int i = 0; i < 4; ++i)
    #pragma unroll
    for (int j = 0; j < 4; ++j) acc[i][j] = (f32x4){0.f, 0.f, 0.f, 0.f};

  for (int kb = 0; kb < KP; kb += 64) {
    __syncthreads();
    #pragma unroll
    for (int c = 0; c < 4; ++c) {
      int lin = c * 256 + tid;
      int row = lin >> 3, col = (lin & 7) * 8;
      *(us8*)(As + row * 64 + col) = *(const us8*)(Ap + (size_t)(mt * 128 + row) * KP + kb + col);
      *(us8*)(Bs + row * 64 + col) = *(const us8*)(Bw + (size_t)(nt * 128 + row) * KP + kb + col);
    }
    __syncthreads();
    #pragma unroll
    for (int ks = 0; ks < 2; ++ks) {
      const int kk = ks * 32 + lq * 8;
      short8 af[4], bf[4];
      #pragma unroll
      for (int i = 0; i < 4; ++i) af[i] = *(const short8*)(As + (wm * 64 + i * 16 + l15) * 64 + kk);
      #pragma unroll
      for (int i = 0; i < 4; ++i) bf[i] = *(const short8*)(Bs + (wn * 64 + i * 16 + l15) * 64 + kk);
      #pragma unroll
      for (int i = 0; i < 4; ++i)
        #pragma unroll
        for (int j = 0; j < 4; ++j)
          acc[i][j] = __builtin_amdgcn_mfma_f32_16x16x32_bf16(af[i], bf[j], acc[i][j], 0, 0, 0);
    }
  }
  #pragma unroll
  for (int j = 0; j < 4; ++j) {
    const int n = nt * 128 + wn * 64 + j * 16 + l15;
    const float bv = bias[n];
    #pragma unroll
    for (int i = 0; i < 4; ++i) {
      const int mrow = mt * 128 + wm * 64 + i * 16 + lq * 4;
      uint16_t* cp = C + (size_t)mrow * KP + n;
      #pragma unroll
      for (int r = 0; r < 4; ++r) cp[(size_t)r * KP] = f2bf(acc[i][j][r] + bv);
    }
  }
}

// ---------------- persistent LSTM recurrence, 2 independent batch groups ----------------
// grid = 128: group g = blockIdx&1 owns samples [g*32, g*32+32); bk = blockIdx>>1 owns
// hidden units [bk*8, bk*8+8). hx in per-step per-group buffers pre-poisoned with
// 0xFFFF (bf16 NaN — unreachable since |h|<=1). Publishers fire sc0/sc1 stores and
// never wait; waiters poll-load the hx DATA directly (batched dwordx4 sc0/sc1 +
// single vmcnt(0)) until no sentinel. This merges {store-ack, flag flight, flag
// discovery, data load} ~4 MALL round trips into ~2. Raw s_barrier (no implicit
// vmcnt drain) for intra-block LDS handoff.
__global__ __launch_bounds__(256, 1) void rec_kernel(
    const uint16_t* __restrict__ WhhH, const uint16_t* __restrict__ WhhL,
    const uint16_t* __restrict__ WihH, const uint16_t* __restrict__ WihL,
    const uint16_t* __restrict__ ApH, const uint16_t* __restrict__ ApL,
    const float* __restrict__ biasg,     // [2048] b_ih+b_hh
    const float* __restrict__ aarr,      // [T_*64] gate a (mask or att*mask)
    uint16_t* __restrict__ hxH,          // this iter's HX hi base (t=0 plane)
    uint16_t* __restrict__ hxL,
    float* __restrict__ last)            // [64][512] fp32: init in, final out
{
  const int tid = threadIdx.x;
  const int g  = blockIdx.x & 1;
  const int bk = blockIdx.x >> 1;
  const int lane = tid & 63, w = tid >> 6;
  const int l15 = lane & 15, lq = lane >> 4;
  const int gh = l15 >> 3, uu = l15 & 7;

  // weight fragments resident in VGPRs: n-tile n2 cols 0..7 -> gate 2*n2, 8..15 -> 2*n2+1
  short8 bhhH[2][4], bhhL[2][4], bihH[2][3], bihL[2][3];
  #pragma unroll
  for (int n2 = 0; n2 < 2; ++n2) {
    const int n = (n2 * 2 + gh) * 512 + bk * 8 + uu;
    #pragma unroll
    for (int ks = 0; ks < 4; ++ks) {
      const size_t off = (size_t)n * 512 + w * 128 + ks * 32 + lq * 8;
      bhhH[n2][ks] = *(const short8*)(WhhH + off);
      bhhL[n2][ks] = *(const short8*)(WhhL + off);
    }
    #pragma unroll
    for (int kb = 0; kb < 3; ++kb) {
      const size_t off = (size_t)n * KP + w * 96 + kb * 32 + lq * 8;
      bihH[n2][kb] = *(const short8*)(WihH + off);
      bihL[n2][kb] = *(const short8*)(WihL + off);
    }
  }

  // epilogue ownership (tid<128): sample eb (group-local), units (eu, eu+1)
  const int eb = tid >> 2;                 // 0..31 for tid<128
  const int eu = (tid & 3) * 2;
  const int gb = g * 32 + eb;              // global batch index
  float2 bg2[4];
  float hprev0 = 0.f, hprev1 = 0.f, cprev0 = 0.f, cprev1 = 0.f;
  if (tid < 128) {
    #pragma unroll
    for (int gg = 0; gg < 4; ++gg) bg2[gg] = *(const float2*)(biasg + gg * 512 + bk * 8 + eu);
    hprev0 = last[gb * 512 + bk * 8 + eu];
    hprev1 = last[gb * 512 + bk * 8 + eu + 1];
  }

  __shared__ float part[4][32][36];        // K-split partials; stride 36 -> 2-way (free)

  #pragma clang loop unroll(disable)
  for (int t = 0; t < T_; ++t) {
    const size_t ap_base = (size_t)t * 64 * KP + (size_t)g * 32 * KP;

    f32x4 acc[2][2];
    #pragma unroll
    for (int mi = 0; mi < 2; ++mi) { acc[mi][0] = (f32x4){0,0,0,0}; acc[mi][1] = (f32x4){0,0,0,0}; }

    // (A) input-side gates: xe @ W_ih^T — no dependence on other blocks
    #pragma unroll
    for (int kb = 0; kb < 3; ++kb) {
      const int k = w * 96 + kb * 32 + lq * 8;
      #pragma unroll
      for (int mi = 0; mi < 2; ++mi) {
        const size_t aoff = ap_base + (size_t)(mi * 16 + l15) * KP + k;
        short8 aH = *(const short8*)(ApH + aoff);
        short8 aL = *(const short8*)(ApL + aoff);
        #pragma unroll
        for (int n2 = 0; n2 < 2; ++n2) {
          acc[mi][n2] = __builtin_amdgcn_mfma_f32_16x16x32_bf16(aH, bihH[n2][kb], acc[mi][n2], 0, 0, 0);
          acc[mi][n2] = __builtin_amdgcn_mfma_f32_16x16x32_bf16(aH, bihL[n2][kb], acc[mi][n2], 0, 0, 0);
          acc[mi][n2] = __builtin_amdgcn_mfma_f32_16x16x32_bf16(aL, bihH[n2][kb], acc[mi][n2], 0, 0, 0);
        }
      }
    }
    const float a = (tid < 128) ? aarr[t * 64 + gb] : 0.f;

    // (B/C) poll-load hx[t] directly (per-wave; sentinel = 0xFFFFFFFF)
    __builtin_amdgcn_sched_barrier(0);     // keep (A) MFMAs ahead of the poll
    const uint16_t* hh = hxH + ((size_t)t * 2 + g) * HXG;
    const uint16_t* hl = hxL + ((size_t)t * 2 + g) * HXG;
    const uint16_t* ah[8];
    #pragma unroll
    for (int ks = 0; ks < 4; ++ks)
      #pragma unroll
      for (int mi = 0; mi < 2; ++mi)
        ah[ks * 2 + mi] = hh + (size_t)(mi * 16 + l15) * 512 + (w * 128 + ks * 32 + lq * 8);
    const ptrdiff_t dlo = hl - hh;
    u32x4 fh[8], fl[8];
    for (;;) {
      #pragma unroll
      for (int i = 0; i < 8; ++i) { ldg_cp16(fh[i], ah[i]); ldg_cp16(fl[i], ah[i] + dlo); }
      asm volatile("s_waitcnt vmcnt(0)" ::: "memory");
      __builtin_amdgcn_sched_barrier(0);   // rule #18: no consumer hoisted above the wait
      unsigned mx = 0u;
      #pragma unroll
      for (int i = 0; i < 8; ++i)
        #pragma unroll
        for (int j = 0; j < 4; ++j) {
          mx = fh[i][j] > mx ? fh[i][j] : mx;
          mx = fl[i][j] > mx ? fl[i][j] : mx;
        }
      if (__all((int)(mx != 0xFFFFFFFFu))) break;
      __builtin_amdgcn_s_sleep(1);
    }

    // recurrent gates: hx[t] @ W_hh^T from polled fragments
    #pragma unroll
    for (int ks = 0; ks < 4; ++ks) {
      #pragma unroll
      for (int mi = 0; mi < 2; ++mi) {
        short8 hH = __builtin_bit_cast(short8, fh[ks * 2 + mi]);
        short8 hL = __builtin_bit_cast(short8, fl[ks * 2 + mi]);
        #pragma unroll
        for (int n2 = 0; n2 < 2; ++n2) {
          acc[mi][n2] = __builtin_amdgcn_mfma_f32_16x16x32_bf16(hH, bhhH[n2][ks], acc[mi][n2], 0, 0, 0);
          acc[mi][n2] = __builtin_amdgcn_mfma_f32_16x16x32_bf16(hH, bhhL[n2][ks], acc[mi][n2], 0, 0, 0);
          acc[mi][n2] = __builtin_amdgcn_mfma_f32_16x16x32_bf16(hL, bhhH[n2][ks], acc[mi][n2], 0, 0, 0);
        }
      }
    }

    // (D) K-partials to LDS: D row=(lq*4+r)=sample, col=l15 within n-tile
    #pragma unroll
    for (int mi = 0; mi < 2; ++mi)
      #pragma unroll
      for (int n2 = 0; n2 < 2; ++n2)
        #pragma unroll
        for (int r = 0; r < 4; ++r)
          part[w][mi * 16 + lq * 4 + r][n2 * 16 + l15] = acc[mi][n2][r];

    // mid-step barrier: publish ds_writes, no vmcnt drain (raw s_barrier)
    asm volatile("s_waitcnt lgkmcnt(0)" ::: "memory");
    __builtin_amdgcn_sched_barrier(0);
    __builtin_amdgcn_s_barrier();
    __builtin_amdgcn_sched_barrier(0);

    // (E) epilogue: gates -> gated (c,h) update; publish hx[t+1] (fire-and-forget)
    if (tid < 128) {
      float gv0[4], gv1[4];
      #pragma unroll
      for (int gg = 0; gg < 4; ++gg) {
        float s0 = bg2[gg].x, s1 = bg2[gg].y;
        #pragma unroll
        for (int ww = 0; ww < 4; ++ww) {
          s0 += part[ww][eb][gg * 8 + eu];
          s1 += part[ww][eb][gg * 8 + eu + 1];
        }
        gv0[gg] = s0; gv1[gg] = s1;
      }
      float i0 = fsig(gv0[0]), f0 = fsig(gv0[1]), g0 = ftanh(gv0[2]), o0 = fsig(gv0[3]);
      float i1 = fsig(gv1[0]), f1 = fsig(gv1[1]), g1 = ftanh(gv1[2]), o1 = fsig(gv1[3]);
      float cn0 = f0 * cprev0 + i0 * g0;
      float cn1 = f1 * cprev1 + i1 * g1;
      float hn0 = o0 * ftanh(cn0);
      float hn1 = o1 * ftanh(cn1);
      float h0 = a * hn0 + (1.f - a) * hprev0;
      float h1 = a * hn1 + (1.f - a) * hprev1;
      cprev0 = a * cn0 + (1.f - a) * cprev0;
      cprev1 = a * cn1 + (1.f - a) * cprev1;
      hprev0 = h0; hprev1 = h1;

      uint16_t b0 = f2bf(h0), b1 = f2bf(h1);
      uint16_t l0 = f2bf(h0 - bf2f(b0)), l1 = f2bf(h1 - bf2f(b1));
      const size_t o = ((size_t)(t + 1) * 2 + g) * HXG + eb * 512 + bk * 8 + eu;
      st_cp((unsigned*)(hxH + o), (uint32_t)b0 | ((uint32_t)b1 << 16));
      st_cp((unsigned*)(hxL + o), (uint32_t)l0 | ((uint32_t)l1 << 16));
      if (t == T_ - 1) {
        float2 lv; lv.x = h0; lv.y = h1;
        *(float2*)(last + gb * 512 + bk * 8 + eu) = lv;
      }
    }
    // end-of-step barrier: protect LDS `part` reuse; raw s_barrier (LDS reads of (E)
    // already consumed into registers; hx stores intentionally left in flight)
    if (t < T_ - 1) {
      __builtin_amdgcn_sched_barrier(0);
      __builtin_amdgcn_s_barrier();
      __builtin_amdgcn_sched_barrier(0);
    }
  }
}

// ---------------- attention between iterations (all fp32) ----------------
__global__ void att1_kernel(const float* __restrict__ last, const float* __restrict__ aW1,
                            float* __restrict__ hterm) {
  int id = blockIdx.x * 256 + threadIdx.x;           // 64*300
  if (id >= 64 * 300) return;
  int b = id / 300, e = id % 300;
  const float* lr = last + b * 512;
  const float* wr = aW1 + (size_t)e * 812 + 300;     // aW1[e, E+k]
  float s = 0.f;
  #pragma unroll 8
  for (int k = 0; k < 512; ++k) s += lr[k] * wr[k];
  hterm[b * 300 + e] = s;
}

__global__ void att2_kernel(const uint16_t* __restrict__ S1, const float* __restrict__ hterm,
                            const float* __restrict__ aW2, const float* __restrict__ ab2,
                            const float* __restrict__ amask, float* __restrict__ att) {
  int id = blockIdx.x * 128 + threadIdx.x;           // t*64+b
  if (id >= BT_) return;
  int b = id & 63;
  const uint16_t* s1 = S1 + (size_t)id * KP;         // inp@aW1[:,:E]^T + ab1 (bf16)
  const float* ht = hterm + b * 300;
  float s = ab2[0];
  for (int e = 0; e < 300; ++e) s += ftanh(bf2f(s1[e]) + ht[e]) * aW2[e];
  att[id] = amask[id] * fsig(s);
}

// ---------------- final logits (fp32 in, fp32 out) ----------------
__global__ void logits_kernel(const float* __restrict__ last, const float* __restrict__ Wout,
                              const float* __restrict__ bout, float* __restrict__ out) {
  int tid = threadIdx.x;                             // 320 = 64*5
  if (tid >= 320) return;
  int b = tid / 5, o = tid % 5;
  const float* lr = last + b * 512;
  const float* wr = Wout + o * 512;
  float s = bout[o];
  #pragma unroll 8
  for (int k = 0; k < 512; ++k) s += lr[k] * wr[k];
  out[tid] = s;
}

// ---------------- workspace layout (bytes, 256-aligned) ----------------
#define OFF_APHI  ((size_t)0)            // 16384*384*2 = 12,582,912
#define OFF_APLO  ((size_t)12582912)
#define OFF_WIHHI ((size_t)25165824)     // 2048*384*2 = 1,572,864
#define OFF_WIHLO ((size_t)26738688)
#define OFF_WHHHI ((size_t)28311552)     // 2048*512*2 = 2,097,152
#define OFF_WHHLO ((size_t)30408704)
#define OFF_AW1E  ((size_t)32505856)     // 384*384*2 = 294,912
#define OFF_S1    ((size_t)32800768)     // 16384*384*2 = 12,582,912 (bf16)
#define OFF_S1B   ((size_t)45383680)     // 1536
#define OFF_BG    ((size_t)45385216)     // 8192
#define OFF_HXH   ((size_t)45393408)     // 513*65536 = 33,619,968
#define OFF_HXL   ((size_t)79013376)     // 33,619,968
#define OFF_AMASK ((size_t)112633344)    // 65,536
#define OFF_ATT   ((size_t)112698880)    // 65,536
#define OFF_HT    ((size_t)112764416)    // 76,800
#define OFF_LAST  ((size_t)112841216)    // 131,072
#define WS_NEED   ((size_t)112972288)

extern "C" void kernel_launch(void* const* d_in, const int* in_sizes, int n_in,
                              void* d_out, int out_size, void* d_ws, size_t ws_size,
                              hipStream_t stream) {
  const float* emb  = (const float*)d_in[0];
  const float* W_ih = (const float*)d_in[1];
  const float* b_ih = (const float*)d_in[2];
  const float* W_hh = (const float*)d_in[3];
  const float* b_hh = (const float*)d_in[4];
  const float* aW1  = (const float*)d_in[5];
  const float* ab1  = (const float*)d_in[6];
  const float* aW2  = (const float*)d_in[7];
  const float* ab2  = (const float*)d_in[8];
  const float* Wout = (const float*)d_in[9];
  const float* bout = (const float*)d_in[10];
  const int*   x    = (const int*)d_in[11];

  if (ws_size < WS_NEED) return;  // guarded fail: d_out stays zero (diagnostic)

  char* ws = (char*)d_ws;
  uint16_t* ApH    = (uint16_t*)(ws + OFF_APHI);
  uint16_t* ApL    = (uint16_t*)(ws + OFF_APLO);
  uint16_t* WihH   = (uint16_t*)(ws + OFF_WIHHI);
  uint16_t* WihL   = (uint16_t*)(ws + OFF_WIHLO);
  uint16_t* WhhH   = (uint16_t*)(ws + OFF_WHHHI);
  uint16_t* WhhL   = (uint16_t*)(ws + OFF_WHHLO);
  uint16_t* AW1e   = (uint16_t*)(ws + OFF_AW1E);
  uint16_t* S1     = (uint16_t*)(ws + OFF_S1);
  float*    s1bias = (float*)(ws + OFF_S1B);
  float*    biasg  = (float*)(ws + OFF_BG);
  uint16_t* HXH    = (uint16_t*)(ws + OFF_HXH);
  uint16_t* HXL    = (uint16_t*)(ws + OFF_HXL);
  float*    amask  = (float*)(ws + OFF_AMASK);
  float*    att    = (float*)(ws + OFF_ATT);
  float*    hterm  = (float*)(ws + OFF_HT);
  float*    last   = (float*)(ws + OFF_LAST);

  prep_kernel<<<24602, 256, 0, stream>>>(emb, W_ih, b_ih, W_hh, b_hh, aW1, ab1, x,
                                         ApH, ApL, WihH, WihL, WhhH, WhhL, AW1e,
                                         s1bias, biasg, HXH, HXL, amask, last);
  gemm_s1<<<dim3(3, 128), 256, 0, stream>>>(ApH, AW1e, s1bias, S1);
  // iter 0: a = pad mask; HX planes [0..256]
  rec_kernel<<<2 * G_, 256, 0, stream>>>(WhhH, WhhL, WihH, WihL, ApH, ApL,
                                         biasg, amask, HXH, HXL, last);
  att1_kernel<<<75, 256, 0, stream>>>(last, aW1, hterm);
  att2_kernel<<<128, 128, 0, stream>>>(S1, hterm, aW2, ab2, amask, att);
  // iter 1: a = attention * mask; HX base shifted so its t=0 plane = iter0's final
  rec_kernel<<<2 * G_, 256, 0, stream>>>(WhhH, WhhL, WihH, WihL, ApH, ApL,
                                         biasg, att, HXH + (size_t)256 * HXS,
                                         HXL + (size_t)256 * HXS, last);
  logits_kernel<<<1, 320, 0, stream>>>(last, Wout, bout, (float*)d_out);
}